// Round 1
// baseline (2280.937 us; speedup 1.0000x reference)
//
#include <hip/hip_runtime.h>
#include <hip/hip_bf16.h>

#define DEV_INLINE __device__ __forceinline__

DEV_INLINE float leaky(float x, float s) { return x >= 0.f ? x : s * x; }

// ---------------------------------------------------------------------------
// CSR build: histogram -> scan -> scatter
// ---------------------------------------------------------------------------
__global__ __launch_bounds__(256) void count_dst_kernel(
    const int* __restrict__ dst, int* __restrict__ counts, int E) {
  int gid = blockIdx.x * 256 + threadIdx.x;
  if (gid < E) atomicAdd(&counts[dst[gid]], 1);
}

__global__ __launch_bounds__(1024) void scan_kernel(
    const int* __restrict__ counts, int* __restrict__ offs,
    int* __restrict__ cursor, int n) {
  __shared__ int sums[1024];
  int t = threadIdx.x;
  int chunk = (n + 1023) / 1024;
  int lo = t * chunk;
  int hi = lo + chunk; if (hi > n) hi = n;
  int s = 0;
  if (lo < n) for (int i = lo; i < hi; ++i) s += counts[i];
  sums[t] = s;
  __syncthreads();
  for (int off = 1; off < 1024; off <<= 1) {
    int v = (t >= off) ? sums[t - off] : 0;
    __syncthreads();
    sums[t] += v;
    __syncthreads();
  }
  int run = (t == 0) ? 0 : sums[t - 1];
  if (lo < n) {
    for (int i = lo; i < hi; ++i) {
      int c = counts[i];          // read first: cursor may alias counts
      offs[i] = run;
      cursor[i] = run;
      run += c;
    }
    if (hi == n) offs[n] = run;   // total = E
  }
}

__global__ __launch_bounds__(256) void scatter_kernel(
    const int* __restrict__ src, const int* __restrict__ dst,
    int* __restrict__ cursor, int* __restrict__ csr_src, int E) {
  int gid = blockIdx.x * 256 + threadIdx.x;
  if (gid < E) {
    int d = dst[gid];
    int pos = atomicAdd(&cursor[d], 1);
    csr_src[pos] = src[gid];
  }
}

// ---------------------------------------------------------------------------
// Encoder big GEMMs: [N,768] @ [768,32], tile 128 nodes x 32 cols, KC=32
// grid.y = 0 -> des (cols 0..31), 1 -> tweet (cols 32..63)
// ---------------------------------------------------------------------------
__global__ __launch_bounds__(256) void enc_big_kernel(
    const float* __restrict__ des, const float* __restrict__ tweet,
    const float* __restrict__ w_des, const float* __restrict__ w_tw,
    const float* __restrict__ b_des, const float* __restrict__ b_tw,
    float* __restrict__ x0, int n_rows) {
  const float* A; const float* W; const float* bias; int col_off;
  if (blockIdx.y == 0) { A = des;   W = w_des; bias = b_des; col_off = 0; }
  else                 { A = tweet; W = w_tw;  bias = b_tw;  col_off = 32; }

  __shared__ float As[32][132];   // [k][node], padded
  __shared__ float Ws[32][36];    // [k][col], padded

  int t = threadIdx.x;
  int node0 = blockIdx.x * 128;
  int cg = t & 7;     // cols cg*4 .. +3
  int ng = t >> 3;    // nodes ng*4 .. +3 (0..31)
  float acc[4][4] = {};

  for (int k0 = 0; k0 < 768; k0 += 32) {
    // stage A: 128 nodes x 32 k = 1024 float4, 4 per thread
    #pragma unroll
    for (int i = 0; i < 4; ++i) {
      int f = t + 256 * i;
      int nd = f >> 3, kq = f & 7;
      int gn = node0 + nd;
      float4 v = make_float4(0.f, 0.f, 0.f, 0.f);
      if (gn < n_rows) v = *(const float4*)&A[(size_t)gn * 768 + k0 + kq * 4];
      As[kq * 4 + 0][nd] = v.x;
      As[kq * 4 + 1][nd] = v.y;
      As[kq * 4 + 2][nd] = v.z;
      As[kq * 4 + 3][nd] = v.w;
    }
    // stage W: 32k x 32c = 256 float4, 1 per thread
    {
      int kk = t >> 3, cq = t & 7;
      float4 v = *(const float4*)&W[(size_t)(k0 + kk) * 32 + cq * 4];
      *(float4*)&Ws[kk][cq * 4] = v;
    }
    __syncthreads();
    #pragma unroll 8
    for (int k = 0; k < 32; ++k) {
      float4 a4 = *(const float4*)&As[k][ng * 4];
      float4 w4 = *(const float4*)&Ws[k][cg * 4];
      float av[4] = {a4.x, a4.y, a4.z, a4.w};
      float wv[4] = {w4.x, w4.y, w4.z, w4.w};
      #pragma unroll
      for (int i = 0; i < 4; ++i)
        #pragma unroll
        for (int j = 0; j < 4; ++j)
          acc[i][j] += av[i] * wv[j];
    }
    __syncthreads();
  }
  #pragma unroll
  for (int i = 0; i < 4; ++i) {
    int gn = node0 + ng * 4 + i;
    if (gn >= n_rows) continue;
    float4 o;
    o.x = leaky(acc[i][0] + bias[cg * 4 + 0], 0.01f);
    o.y = leaky(acc[i][1] + bias[cg * 4 + 1], 0.01f);
    o.z = leaky(acc[i][2] + bias[cg * 4 + 2], 0.01f);
    o.w = leaky(acc[i][3] + bias[cg * 4 + 3], 0.01f);
    *(float4*)&x0[(size_t)gn * 128 + col_off + cg * 4] = o;
  }
}

// ---------------------------------------------------------------------------
// Encoder small GEMMs: num_prop (K=6) -> cols 64..95, cat_prop (K=11) -> 96..127
// ---------------------------------------------------------------------------
__global__ __launch_bounds__(256) void enc_small_kernel(
    const float* __restrict__ np_, const float* __restrict__ cp,
    const float* __restrict__ w_np, const float* __restrict__ w_cp,
    const float* __restrict__ b_np, const float* __restrict__ b_cp,
    float* __restrict__ x0, int n_rows) {
  int gid = blockIdx.x * 256 + threadIdx.x;
  int node = gid >> 6;
  int c = gid & 63;
  if (node >= n_rows) return;
  float acc; int col;
  if (c < 32) {
    acc = b_np[c];
    #pragma unroll
    for (int k = 0; k < 6; ++k) acc += np_[(size_t)node * 6 + k] * w_np[k * 32 + c];
    col = 64 + c;
  } else {
    int cc = c - 32;
    acc = b_cp[cc];
    #pragma unroll
    for (int k = 0; k < 11; ++k) acc += cp[(size_t)node * 11 + k] * w_cp[k * 32 + cc];
    col = 96 + cc;
  }
  x0[(size_t)node * 128 + col] = leaky(acc, 0.01f);
}

// ---------------------------------------------------------------------------
// Generic dense: Y[n][c] = act(sum_k X[n][k] W[k][c] + b[c]), K=C=128
// Tile 64 nodes x 128 cols, KC=64, thread = 4 nodes x 8 cols
// ---------------------------------------------------------------------------
template <bool LEAKY, bool BIAS>
__global__ __launch_bounds__(256) void dense128_kernel(
    const float* __restrict__ X, const float* __restrict__ W,
    const float* __restrict__ bias, float* __restrict__ Y, int n_rows) {
  __shared__ float As[64][68];    // [k][node]
  __shared__ float Ws[64][132];   // [k][col]
  int t = threadIdx.x;
  int node0 = blockIdx.x * 64;
  int cg = t & 15;    // cols cg*8 .. +7
  int ng = t >> 4;    // nodes ng*4 .. +3
  float acc[4][8] = {};

  for (int k0 = 0; k0 < 128; k0 += 64) {
    // stage A: 64 nodes x 64 k = 1024 float4, 4 per thread
    #pragma unroll
    for (int i = 0; i < 4; ++i) {
      int f = t + 256 * i;
      int nd = f >> 4, kq = f & 15;
      int gn = node0 + nd;
      float4 v = make_float4(0.f, 0.f, 0.f, 0.f);
      if (gn < n_rows) v = *(const float4*)&X[(size_t)gn * 128 + k0 + kq * 4];
      As[kq * 4 + 0][nd] = v.x;
      As[kq * 4 + 1][nd] = v.y;
      As[kq * 4 + 2][nd] = v.z;
      As[kq * 4 + 3][nd] = v.w;
    }
    // stage W: 64k x 128c = 2048 float4, 8 per thread
    #pragma unroll
    for (int i = 0; i < 8; ++i) {
      int f = t + 256 * i;
      int kk = f >> 5, cq = f & 31;
      float4 v = *(const float4*)&W[(size_t)(k0 + kk) * 128 + cq * 4];
      *(float4*)&Ws[kk][cq * 4] = v;
    }
    __syncthreads();
    #pragma unroll 4
    for (int k = 0; k < 64; ++k) {
      float4 a4 = *(const float4*)&As[k][ng * 4];
      float4 w0 = *(const float4*)&Ws[k][cg * 8];
      float4 w1 = *(const float4*)&Ws[k][cg * 8 + 4];
      float av[4] = {a4.x, a4.y, a4.z, a4.w};
      float wv[8] = {w0.x, w0.y, w0.z, w0.w, w1.x, w1.y, w1.z, w1.w};
      #pragma unroll
      for (int i = 0; i < 4; ++i)
        #pragma unroll
        for (int j = 0; j < 8; ++j)
          acc[i][j] += av[i] * wv[j];
    }
    __syncthreads();
  }
  #pragma unroll
  for (int i = 0; i < 4; ++i) {
    int gn = node0 + ng * 4 + i;
    if (gn >= n_rows) continue;
    float o[8];
    #pragma unroll
    for (int j = 0; j < 8; ++j) {
      float v = acc[i][j];
      if (BIAS) v += bias[cg * 8 + j];
      if (LEAKY) v = leaky(v, 0.01f);
      o[j] = v;
    }
    *(float4*)&Y[(size_t)gn * 128 + cg * 8]     = make_float4(o[0], o[1], o[2], o[3]);
    *(float4*)&Y[(size_t)gn * 128 + cg * 8 + 4] = make_float4(o[4], o[5], o[6], o[7]);
  }
}

// ---------------------------------------------------------------------------
// Attention logit dots: a_s[n][h] = sum_c h[n][h*C+c]*att_s[h*C+c], same a_d
// One wave per node; lane handles 2 channels.
// ---------------------------------------------------------------------------
template <int H>
__global__ __launch_bounds__(256) void att_dots_kernel(
    const float* __restrict__ h, const float* __restrict__ att_s,
    const float* __restrict__ att_d, float* __restrict__ a_s,
    float* __restrict__ a_d, int n_rows) {
  int wave = (blockIdx.x * 256 + threadIdx.x) >> 6;
  int lane = threadIdx.x & 63;
  if (wave >= n_rows) return;
  int c = lane * 2;
  float2 hv = *(const float2*)&h[(size_t)wave * 128 + c];
  float2 sv = *(const float2*)&att_s[c];
  float2 dv = *(const float2*)&att_d[c];
  float ps = hv.x * sv.x + hv.y * sv.y;
  float pd = hv.x * dv.x + hv.y * dv.y;
  const int G = 64 / H;   // lanes per head group
  #pragma unroll
  for (int o = 1; o < G; o <<= 1) {
    ps += __shfl_xor(ps, o, 64);
    pd += __shfl_xor(pd, o, 64);
  }
  if ((lane & (G - 1)) == 0) {
    int head = lane / G;
    a_s[(size_t)wave * H + head] = ps;
    a_d[(size_t)wave * H + head] = pd;
  }
}

// ---------------------------------------------------------------------------
// GAT aggregation with online softmax. One wave per destination node.
// Lane handles channels 2l, 2l+1; head = channel / (128/H).
// Self-loop included implicitly.
// ---------------------------------------------------------------------------
template <int H>
__global__ __launch_bounds__(256) void agg_kernel(
    const float* __restrict__ h, const float* __restrict__ a_src,
    const float* __restrict__ a_dst, const int* __restrict__ offs,
    const int* __restrict__ csr_src, const float* __restrict__ bias,
    float* __restrict__ out, int n_rows) {
  int n = (blockIdx.x * 256 + threadIdx.x) >> 6;
  int lane = threadIdx.x & 63;
  if (n >= n_rows) return;
  int c = lane * 2;
  const int C = 128 / H;
  int head = c / C;

  float ad = a_dst[(size_t)n * H + head];
  // self-loop: alpha = leaky(a_s[n]+a_d[n]); seeds the online softmax
  float m = leaky(a_src[(size_t)n * H + head] + ad, 0.2f);
  float l = 1.0f;
  float2 hv = *(const float2*)&h[(size_t)n * 128 + c];
  float acc0 = hv.x, acc1 = hv.y;

  int e0 = offs[n], e1 = offs[n + 1];
  for (int e = e0; e < e1; ++e) {
    int s = csr_src[e];   // wave-uniform
    float a = leaky(a_src[(size_t)s * H + head] + ad, 0.2f);
    float mn = fmaxf(m, a);
    float scale = __expf(m - mn);
    float ex = __expf(a - mn);
    float2 hs = *(const float2*)&h[(size_t)s * 128 + c];
    l = l * scale + ex;
    acc0 = acc0 * scale + ex * hs.x;
    acc1 = acc1 * scale + ex * hs.y;
    m = mn;
  }
  float inv = 1.0f / (l + 1e-16f);
  out[(size_t)n * 128 + c]     = acc0 * inv + bias[c];
  out[(size_t)n * 128 + c + 1] = acc1 * inv + bias[c + 1];
}

// ---------------------------------------------------------------------------
// Final MLP tail: out[n][j] = t[n] . w_o2[:,j] + b_o2[j], j in {0,1}
// ---------------------------------------------------------------------------
__global__ __launch_bounds__(256) void final2_kernel(
    const float* __restrict__ tt, const float* __restrict__ w,
    const float* __restrict__ b, float* __restrict__ out, int n_rows) {
  int gid = blockIdx.x * 256 + threadIdx.x;
  if (gid >= n_rows) return;
  float a0 = b[0], a1 = b[1];
  #pragma unroll 4
  for (int k = 0; k < 128; k += 4) {
    float4 v = *(const float4*)&tt[(size_t)gid * 128 + k];
    a0 += v.x * w[k * 2 + 0] + v.y * w[k * 2 + 2] + v.z * w[k * 2 + 4] + v.w * w[k * 2 + 6];
    a1 += v.x * w[k * 2 + 1] + v.y * w[k * 2 + 3] + v.z * w[k * 2 + 5] + v.w * w[k * 2 + 7];
  }
  out[(size_t)gid * 2 + 0] = a0;
  out[(size_t)gid * 2 + 1] = a1;
}

// ---------------------------------------------------------------------------
extern "C" void kernel_launch(void* const* d_in, const int* in_sizes, int n_in,
                              void* d_out, int out_size, void* d_ws, size_t ws_size,
                              hipStream_t stream) {
  const float* des      = (const float*)d_in[0];
  const float* tweet    = (const float*)d_in[1];
  const float* num_prop = (const float*)d_in[2];
  const float* cat_prop = (const float*)d_in[3];
  const int*   ei       = (const int*)d_in[4];
  // d_in[5] = edge_type (unused by reference)
  const float* w_des = (const float*)d_in[6];
  const float* b_des = (const float*)d_in[7];
  const float* w_tw  = (const float*)d_in[8];
  const float* b_tw  = (const float*)d_in[9];
  const float* w_np  = (const float*)d_in[10];
  const float* b_np  = (const float*)d_in[11];
  const float* w_cp  = (const float*)d_in[12];
  const float* b_cp  = (const float*)d_in[13];
  const float* w_in  = (const float*)d_in[14];
  const float* b_in  = (const float*)d_in[15];
  const float* g1_w  = (const float*)d_in[16];
  const float* g1_as = (const float*)d_in[17];
  const float* g1_ad = (const float*)d_in[18];
  const float* g1_b  = (const float*)d_in[19];
  const float* g2_w  = (const float*)d_in[20];
  const float* g2_as = (const float*)d_in[21];
  const float* g2_ad = (const float*)d_in[22];
  const float* g2_b  = (const float*)d_in[23];
  const float* w_o1  = (const float*)d_in[24];
  const float* b_o1  = (const float*)d_in[25];
  const float* w_o2  = (const float*)d_in[26];
  const float* b_o2  = (const float*)d_in[27];

  const int N = in_sizes[0] / 768;
  const int E = in_sizes[4] / 2;
  const int* src = ei;
  const int* dst = ei + E;

  // workspace layout (all 4-byte elements)
  float* bufA = (float*)d_ws;                 // N*128
  float* bufB = bufA + (size_t)N * 128;       // N*128
  float* as1  = bufB + (size_t)N * 128;       // N*4
  float* ad1  = as1 + (size_t)N * 4;          // N*4
  float* as2  = ad1 + (size_t)N * 4;          // N
  float* ad2  = as2 + N;                      // N
  int* counts = (int*)(ad2 + N);              // N (also reused as cursor)
  int* offs   = counts + N;                   // N+1
  int* csr    = offs + N + 1;                 // E

  // ---- CSR build ----
  hipMemsetAsync(counts, 0, (size_t)N * 4, stream);
  count_dst_kernel<<<(E + 255) / 256, 256, 0, stream>>>(dst, counts, E);
  scan_kernel<<<1, 1024, 0, stream>>>(counts, offs, counts, N);
  scatter_kernel<<<(E + 255) / 256, 256, 0, stream>>>(src, dst, counts, csr, E);

  // ---- encoders -> bufA = x0 ----
  dim3 gbig((N + 127) / 128, 2);
  enc_big_kernel<<<gbig, 256, 0, stream>>>(des, tweet, w_des, w_tw, b_des, b_tw, bufA, N);
  enc_small_kernel<<<((size_t)N * 64 + 255) / 256, 256, 0, stream>>>(
      num_prop, cat_prop, w_np, w_cp, b_np, b_cp, bufA, N);

  int gd = (N + 63) / 64;
  int gw = ((size_t)N * 64 + 255) / 256;   // one wave per node

  // ---- x = leaky(x0 @ w_in + b_in) -> bufB ----
  dense128_kernel<true, true><<<gd, 256, 0, stream>>>(bufA, w_in, b_in, bufB, N);

  // ---- GAT1 ----
  dense128_kernel<false, false><<<gd, 256, 0, stream>>>(bufB, g1_w, nullptr, bufA, N);  // h1
  att_dots_kernel<4><<<gw, 256, 0, stream>>>(bufA, g1_as, g1_ad, as1, ad1, N);
  agg_kernel<4><<<gw, 256, 0, stream>>>(bufA, as1, ad1, offs, csr, g1_b, bufB, N);      // x1

  // ---- GAT2 ----
  dense128_kernel<false, false><<<gd, 256, 0, stream>>>(bufB, g2_w, nullptr, bufA, N);  // h2
  att_dots_kernel<1><<<gw, 256, 0, stream>>>(bufA, g2_as, g2_ad, as2, ad2, N);
  agg_kernel<1><<<gw, 256, 0, stream>>>(bufA, as2, ad2, offs, csr, g2_b, bufB, N);      // x2

  // ---- output MLP ----
  dense128_kernel<true, true><<<gd, 256, 0, stream>>>(bufB, w_o1, b_o1, bufA, N);       // t
  final2_kernel<<<(N + 255) / 256, 256, 0, stream>>>(bufA, w_o2, b_o2, (float*)d_out, N);
}

// Round 2
// 1697.944 us; speedup vs baseline: 1.3434x; 1.3434x over previous
//
#include <hip/hip_runtime.h>
#include <hip/hip_bf16.h>

#define DEV_INLINE __device__ __forceinline__

using bf16x8 = __attribute__((ext_vector_type(8))) short;
using f32x4  = __attribute__((ext_vector_type(4))) float;

DEV_INLINE float leaky(float x, float s) { return x >= 0.f ? x : s * x; }
DEV_INLINE float bf2f(unsigned short u) { return __uint_as_float(((unsigned)u) << 16); }
DEV_INLINE unsigned short f2bf(float f) {           // round-to-nearest-even
  unsigned u = __float_as_uint(f);
  unsigned r = ((u >> 16) & 1u) + 0x7fffu;
  return (unsigned short)((u + r) >> 16);
}

// ---------------------------------------------------------------------------
// CSR build: histogram -> scan -> scatter
// ---------------------------------------------------------------------------
__global__ __launch_bounds__(256) void count_dst_kernel(
    const int* __restrict__ dst, int* __restrict__ counts, int E) {
  int gid = blockIdx.x * 256 + threadIdx.x;
  if (gid < E) atomicAdd(&counts[dst[gid]], 1);
}

__global__ __launch_bounds__(1024) void scan_kernel(
    const int* __restrict__ counts, int* __restrict__ offs,
    int* __restrict__ cursor, int n) {
  __shared__ int sums[1024];
  int t = threadIdx.x;
  int chunk = (n + 1023) / 1024;
  int lo = t * chunk;
  int hi = lo + chunk; if (hi > n) hi = n;
  int s = 0;
  if (lo < n) for (int i = lo; i < hi; ++i) s += counts[i];
  sums[t] = s;
  __syncthreads();
  for (int off = 1; off < 1024; off <<= 1) {
    int v = (t >= off) ? sums[t - off] : 0;
    __syncthreads();
    sums[t] += v;
    __syncthreads();
  }
  int run = (t == 0) ? 0 : sums[t - 1];
  if (lo < n) {
    for (int i = lo; i < hi; ++i) {
      int c = counts[i];          // read first: cursor may alias counts
      offs[i] = run;
      cursor[i] = run;
      run += c;
    }
    if (hi == n) offs[n] = run;   // total = E
  }
}

__global__ __launch_bounds__(256) void scatter_kernel(
    const int* __restrict__ src, const int* __restrict__ dst,
    int* __restrict__ cursor, int* __restrict__ csr_src, int E) {
  int gid = blockIdx.x * 256 + threadIdx.x;
  if (gid < E) {
    int d = dst[gid];
    int pos = atomicAdd(&cursor[d], 1);
    csr_src[pos] = src[gid];
  }
}

// ---------------------------------------------------------------------------
// Weight swizzle for MFMA B-fragments (bf16):
// Wsw[((ks*CT + ct)*64 + L)*8 + j] = W[ks*32 + (L>>4)*8 + j][ct*16 + (L&15)]
// blockIdx.y selects which weight. All tiny; runs once per call.
// ---------------------------------------------------------------------------
__global__ __launch_bounds__(256) void swz_kernel(
    const float* __restrict__ w_des, const float* __restrict__ w_tw,
    const float* __restrict__ w_in, const float* __restrict__ g1_w,
    const float* __restrict__ g2_w, const float* __restrict__ w_o1,
    short* __restrict__ o_des, short* __restrict__ o_tw,
    short* __restrict__ o_in, short* __restrict__ o_g1,
    short* __restrict__ o_g2, short* __restrict__ o_o1) {
  const float* W; short* O; int K, COLS;
  switch (blockIdx.y) {
    case 0: W = w_des; O = o_des; K = 768; COLS = 32; break;
    case 1: W = w_tw;  O = o_tw;  K = 768; COLS = 32; break;
    case 2: W = w_in;  O = o_in;  K = 128; COLS = 128; break;
    case 3: W = g1_w;  O = o_g1;  K = 128; COLS = 128; break;
    case 4: W = g2_w;  O = o_g2;  K = 128; COLS = 128; break;
    default: W = w_o1; O = o_o1;  K = 128; COLS = 128; break;
  }
  int CT = COLS >> 4;
  int t = blockIdx.x * 256 + threadIdx.x;
  int total = (K >> 5) * CT * 64;
  if (t >= total) return;
  int L = t & 63;
  int rest = t >> 6;
  int ct = rest % CT;
  int ks = rest / CT;
  int kbase = ks * 32 + (L >> 4) * 8;
  int col = ct * 16 + (L & 15);
  #pragma unroll
  for (int j = 0; j < 8; ++j)
    O[t * 8 + j] = (short)f2bf(W[(size_t)(kbase + j) * COLS + col]);
}

// ---------------------------------------------------------------------------
// Encoder GEMMs via MFMA: [N,768]_f32 @ [768,32] -> x0 cols {0..31 | 32..63}
// block=256 (4 waves); wave = 16 rows x 32 cols; K-loop 24 x 32.
// ---------------------------------------------------------------------------
__global__ __launch_bounds__(256) void enc_mfma_kernel(
    const float* __restrict__ des, const float* __restrict__ tweet,
    const short* __restrict__ wsw_des, const short* __restrict__ wsw_tw,
    const float* __restrict__ b_des, const float* __restrict__ b_tw,
    unsigned short* __restrict__ x0, int n_rows) {
  const float* A; const short* Wsw; const float* bias; int col_off;
  if (blockIdx.y == 0) { A = des;   Wsw = wsw_des; bias = b_des; col_off = 0; }
  else                 { A = tweet; Wsw = wsw_tw;  bias = b_tw;  col_off = 32; }
  int wv = threadIdx.x >> 6, lane = threadIdx.x & 63;
  int row0 = blockIdx.x * 64 + wv * 16;
  int rA = row0 + (lane & 15);
  int rc = rA < n_rows ? rA : (n_rows - 1);
  const float* arow = A + (size_t)rc * 768 + ((lane >> 4) * 8);
  f32x4 acc0 = {0.f, 0.f, 0.f, 0.f}, acc1 = {0.f, 0.f, 0.f, 0.f};
  for (int ks = 0; ks < 24; ++ks) {
    float4 a0 = *(const float4*)(arow + ks * 32);
    float4 a1 = *(const float4*)(arow + ks * 32 + 4);
    bf16x8 af;
    af[0] = (short)f2bf(a0.x); af[1] = (short)f2bf(a0.y);
    af[2] = (short)f2bf(a0.z); af[3] = (short)f2bf(a0.w);
    af[4] = (short)f2bf(a1.x); af[5] = (short)f2bf(a1.y);
    af[6] = (short)f2bf(a1.z); af[7] = (short)f2bf(a1.w);
    bf16x8 b0 = *(const bf16x8*)&Wsw[(size_t)((ks * 2 + 0) * 64 + lane) * 8];
    bf16x8 b1 = *(const bf16x8*)&Wsw[(size_t)((ks * 2 + 1) * 64 + lane) * 8];
    acc0 = __builtin_amdgcn_mfma_f32_16x16x32_bf16(af, b0, acc0, 0, 0, 0);
    acc1 = __builtin_amdgcn_mfma_f32_16x16x32_bf16(af, b1, acc1, 0, 0, 0);
  }
  int quad = lane >> 4, cl = lane & 15;
  #pragma unroll
  for (int r = 0; r < 4; ++r) {
    int row = row0 + quad * 4 + r;
    if (row >= n_rows) continue;
    float v0 = leaky(acc0[r] + bias[cl], 0.01f);
    float v1 = leaky(acc1[r] + bias[16 + cl], 0.01f);
    x0[(size_t)row * 128 + col_off + cl]      = f2bf(v0);
    x0[(size_t)row * 128 + col_off + 16 + cl] = f2bf(v1);
  }
}

// ---------------------------------------------------------------------------
// Encoder small GEMMs: num_prop (K=6) -> cols 64..95, cat_prop (K=11) -> 96..127
// ---------------------------------------------------------------------------
__global__ __launch_bounds__(256) void enc_small_kernel(
    const float* __restrict__ np_, const float* __restrict__ cp,
    const float* __restrict__ w_np, const float* __restrict__ w_cp,
    const float* __restrict__ b_np, const float* __restrict__ b_cp,
    unsigned short* __restrict__ x0, int n_rows) {
  int gid = blockIdx.x * 256 + threadIdx.x;
  int node = gid >> 6;
  int c = gid & 63;
  if (node >= n_rows) return;
  float acc; int col;
  if (c < 32) {
    acc = b_np[c];
    #pragma unroll
    for (int k = 0; k < 6; ++k) acc += np_[(size_t)node * 6 + k] * w_np[k * 32 + c];
    col = 64 + c;
  } else {
    int cc = c - 32;
    acc = b_cp[cc];
    #pragma unroll
    for (int k = 0; k < 11; ++k) acc += cp[(size_t)node * 11 + k] * w_cp[k * 32 + cc];
    col = 96 + cc;
  }
  x0[(size_t)node * 128 + col] = f2bf(leaky(acc, 0.01f));
}

// ---------------------------------------------------------------------------
// Dense 128x128 via MFMA: Y[n][c] = act(sum_k X[n][k] W[k][c] + b[c])
// X bf16 [N][128], Wsw pre-swizzled bf16, Y bf16 [N][128].
// block=256 (4 waves); wave = 16 rows x 128 cols (8 tiles); K-loop 4 x 32.
// ---------------------------------------------------------------------------
template <bool LEAKY, bool BIAS>
__global__ __launch_bounds__(256) void dense_mfma_kernel(
    const unsigned short* __restrict__ X, const short* __restrict__ Wsw,
    const float* __restrict__ bias, unsigned short* __restrict__ Y, int n_rows) {
  int wv = threadIdx.x >> 6, lane = threadIdx.x & 63;
  int row0 = blockIdx.x * 64 + wv * 16;
  int rA = row0 + (lane & 15);
  int rc = rA < n_rows ? rA : (n_rows - 1);
  const unsigned short* xr = X + (size_t)rc * 128 + (lane >> 4) * 8;
  f32x4 acc[8] = {};
  #pragma unroll
  for (int ks = 0; ks < 4; ++ks) {
    bf16x8 af = *(const bf16x8*)(xr + ks * 32);
    #pragma unroll
    for (int ct = 0; ct < 8; ++ct) {
      bf16x8 bfr = *(const bf16x8*)&Wsw[(size_t)((ks * 8 + ct) * 64 + lane) * 8];
      acc[ct] = __builtin_amdgcn_mfma_f32_16x16x32_bf16(af, bfr, acc[ct], 0, 0, 0);
    }
  }
  int quad = lane >> 4, cl = lane & 15;
  #pragma unroll
  for (int r = 0; r < 4; ++r) {
    int row = row0 + quad * 4 + r;
    if (row >= n_rows) continue;
    #pragma unroll
    for (int ct = 0; ct < 8; ++ct) {
      float v = acc[ct][r];
      int col = ct * 16 + cl;
      if (BIAS) v += bias[col];
      if (LEAKY) v = leaky(v, 0.01f);
      Y[(size_t)row * 128 + col] = f2bf(v);
    }
  }
}

// ---------------------------------------------------------------------------
// Attention logit dots (h bf16): a_s[n][h], a_d[n][h]
// ---------------------------------------------------------------------------
template <int H>
__global__ __launch_bounds__(256) void att_dots_kernel(
    const ushort2* __restrict__ h2, const float* __restrict__ att_s,
    const float* __restrict__ att_d, float* __restrict__ a_s,
    float* __restrict__ a_d, int n_rows) {
  int wave = (blockIdx.x * 256 + threadIdx.x) >> 6;
  int lane = threadIdx.x & 63;
  if (wave >= n_rows) return;
  int c = lane * 2;
  ushort2 hv2 = h2[(size_t)wave * 64 + lane];
  float hx = bf2f(hv2.x), hy = bf2f(hv2.y);
  float2 sv = *(const float2*)&att_s[c];
  float2 dv = *(const float2*)&att_d[c];
  float ps = hx * sv.x + hy * sv.y;
  float pd = hx * dv.x + hy * dv.y;
  const int G = 64 / H;   // lanes per head group
  #pragma unroll
  for (int o = 1; o < G; o <<= 1) {
    ps += __shfl_xor(ps, o, 64);
    pd += __shfl_xor(pd, o, 64);
  }
  if ((lane & (G - 1)) == 0) {
    int head = lane / G;
    a_s[(size_t)wave * H + head] = ps;
    a_d[(size_t)wave * H + head] = pd;
  }
}

// ---------------------------------------------------------------------------
// GAT aggregation, online softmax, unroll-4 deferred rescale. Wave per dst.
// h bf16 [N][128] (as ushort2 rows of 64). Self-loop seeds the softmax.
// ---------------------------------------------------------------------------
template <int H>
__global__ __launch_bounds__(256) void agg_kernel(
    const ushort2* __restrict__ h2, const float* __restrict__ a_src,
    const float* __restrict__ a_dst, const int* __restrict__ offs,
    const int* __restrict__ csr_src, const float* __restrict__ bias,
    unsigned short* __restrict__ out, int n_rows) {
  int n = (blockIdx.x * 256 + threadIdx.x) >> 6;
  int lane = threadIdx.x & 63;
  if (n >= n_rows) return;
  int c = lane * 2;
  int head = (c * H) >> 7;

  float ad = a_dst[(size_t)n * H + head];
  float m = leaky(a_src[(size_t)n * H + head] + ad, 0.2f);
  float l = 1.0f;
  ushort2 hv = h2[(size_t)n * 64 + lane];
  float acc0 = bf2f(hv.x), acc1 = bf2f(hv.y);

  int e = offs[n], e1 = offs[n + 1];
  for (; e + 4 <= e1; e += 4) {
    int s0 = csr_src[e], s1 = csr_src[e + 1], s2 = csr_src[e + 2], s3 = csr_src[e + 3];
    float a0 = leaky(a_src[(size_t)s0 * H + head] + ad, 0.2f);
    float a1 = leaky(a_src[(size_t)s1 * H + head] + ad, 0.2f);
    float a2 = leaky(a_src[(size_t)s2 * H + head] + ad, 0.2f);
    float a3 = leaky(a_src[(size_t)s3 * H + head] + ad, 0.2f);
    ushort2 g0 = h2[(size_t)s0 * 64 + lane];
    ushort2 g1 = h2[(size_t)s1 * 64 + lane];
    ushort2 g2 = h2[(size_t)s2 * 64 + lane];
    ushort2 g3 = h2[(size_t)s3 * 64 + lane];
    float mn = fmaxf(fmaxf(fmaxf(a0, a1), fmaxf(a2, a3)), m);
    float sc = __expf(m - mn);
    float x0_ = __expf(a0 - mn), x1_ = __expf(a1 - mn);
    float x2_ = __expf(a2 - mn), x3_ = __expf(a3 - mn);
    l = l * sc + x0_ + x1_ + x2_ + x3_;
    acc0 = acc0 * sc + x0_ * bf2f(g0.x) + x1_ * bf2f(g1.x) + x2_ * bf2f(g2.x) + x3_ * bf2f(g3.x);
    acc1 = acc1 * sc + x0_ * bf2f(g0.y) + x1_ * bf2f(g1.y) + x2_ * bf2f(g2.y) + x3_ * bf2f(g3.y);
    m = mn;
  }
  for (; e < e1; ++e) {
    int s = csr_src[e];
    float a = leaky(a_src[(size_t)s * H + head] + ad, 0.2f);
    float mn = fmaxf(m, a);
    float sc = __expf(m - mn), ex = __expf(a - mn);
    ushort2 g = h2[(size_t)s * 64 + lane];
    l = l * sc + ex;
    acc0 = acc0 * sc + ex * bf2f(g.x);
    acc1 = acc1 * sc + ex * bf2f(g.y);
    m = mn;
  }
  float inv = 1.0f / (l + 1e-16f);
  out[(size_t)n * 128 + c]     = f2bf(acc0 * inv + bias[c]);
  out[(size_t)n * 128 + c + 1] = f2bf(acc1 * inv + bias[c + 1]);
}

// ---------------------------------------------------------------------------
// Final MLP tail: out[n][j] = t[n] . w_o2[:,j] + b_o2[j]  (t is bf16)
// ---------------------------------------------------------------------------
__global__ __launch_bounds__(256) void final2_kernel(
    const unsigned short* __restrict__ tt, const float* __restrict__ w,
    const float* __restrict__ b, float* __restrict__ out, int n_rows) {
  int gid = blockIdx.x * 256 + threadIdx.x;
  if (gid >= n_rows) return;
  const uint4* tp = (const uint4*)(tt + (size_t)gid * 128);
  float a0 = b[0], a1 = b[1];
  #pragma unroll 4
  for (int q = 0; q < 16; ++q) {
    uint4 raw = tp[q];
    unsigned vals[4] = {raw.x, raw.y, raw.z, raw.w};
    #pragma unroll
    for (int i = 0; i < 4; ++i) {
      float f0 = bf2f((unsigned short)(vals[i] & 0xffffu));
      float f1 = bf2f((unsigned short)(vals[i] >> 16));
      int k = q * 8 + i * 2;
      a0 += f0 * w[k * 2]     + f1 * w[(k + 1) * 2];
      a1 += f0 * w[k * 2 + 1] + f1 * w[(k + 1) * 2 + 1];
    }
  }
  out[(size_t)gid * 2 + 0] = a0;
  out[(size_t)gid * 2 + 1] = a1;
}

// ---------------------------------------------------------------------------
static inline size_t align256(size_t x) { return (x + 255) & ~(size_t)255; }

extern "C" void kernel_launch(void* const* d_in, const int* in_sizes, int n_in,
                              void* d_out, int out_size, void* d_ws, size_t ws_size,
                              hipStream_t stream) {
  const float* des      = (const float*)d_in[0];
  const float* tweet    = (const float*)d_in[1];
  const float* num_prop = (const float*)d_in[2];
  const float* cat_prop = (const float*)d_in[3];
  const int*   ei       = (const int*)d_in[4];
  const float* w_des = (const float*)d_in[6];
  const float* b_des = (const float*)d_in[7];
  const float* w_tw  = (const float*)d_in[8];
  const float* b_tw  = (const float*)d_in[9];
  const float* w_np  = (const float*)d_in[10];
  const float* b_np  = (const float*)d_in[11];
  const float* w_cp  = (const float*)d_in[12];
  const float* b_cp  = (const float*)d_in[13];
  const float* w_in  = (const float*)d_in[14];
  const float* b_in  = (const float*)d_in[15];
  const float* g1_w  = (const float*)d_in[16];
  const float* g1_as = (const float*)d_in[17];
  const float* g1_ad = (const float*)d_in[18];
  const float* g1_b  = (const float*)d_in[19];
  const float* g2_w  = (const float*)d_in[20];
  const float* g2_as = (const float*)d_in[21];
  const float* g2_ad = (const float*)d_in[22];
  const float* g2_b  = (const float*)d_in[23];
  const float* w_o1  = (const float*)d_in[24];
  const float* b_o1  = (const float*)d_in[25];
  const float* w_o2  = (const float*)d_in[26];
  const float* b_o2  = (const float*)d_in[27];

  const int N = in_sizes[0] / 768;
  const int E = in_sizes[4] / 2;
  const int* src = ei;
  const int* dst = ei + E;

  // ---- workspace layout (256B aligned segments) ----
  char* p = (char*)d_ws;
  unsigned short* bufA = (unsigned short*)p; p += align256((size_t)N * 128 * 2);
  unsigned short* bufB = (unsigned short*)p; p += align256((size_t)N * 128 * 2);
  float* as1 = (float*)p; p += align256((size_t)N * 4 * 4);
  float* ad1 = (float*)p; p += align256((size_t)N * 4 * 4);
  float* as2 = (float*)p; p += align256((size_t)N * 4);
  float* ad2 = (float*)p; p += align256((size_t)N * 4);
  int* counts = (int*)p; p += align256((size_t)N * 4);
  int* offs   = (int*)p; p += align256((size_t)(N + 1) * 4);
  int* csr    = (int*)p; p += align256((size_t)E * 4);
  short* sw_des = (short*)p; p += align256(768 * 32 * 2);
  short* sw_tw  = (short*)p; p += align256(768 * 32 * 2);
  short* sw_in  = (short*)p; p += align256(128 * 128 * 2);
  short* sw_g1  = (short*)p; p += align256(128 * 128 * 2);
  short* sw_g2  = (short*)p; p += align256(128 * 128 * 2);
  short* sw_o1  = (short*)p; p += align256(128 * 128 * 2);

  // ---- weight swizzle (tiny) ----
  dim3 gswz(12, 6);
  swz_kernel<<<gswz, 256, 0, stream>>>(w_des, w_tw, w_in, g1_w, g2_w, w_o1,
                                       sw_des, sw_tw, sw_in, sw_g1, sw_g2, sw_o1);

  // ---- CSR build ----
  hipMemsetAsync(counts, 0, (size_t)N * 4, stream);
  count_dst_kernel<<<(E + 255) / 256, 256, 0, stream>>>(dst, counts, E);
  scan_kernel<<<1, 1024, 0, stream>>>(counts, offs, counts, N);
  scatter_kernel<<<(E + 255) / 256, 256, 0, stream>>>(src, dst, counts, csr, E);

  // ---- encoders -> bufA = x0 (bf16) ----
  dim3 genc((N + 63) / 64, 2);
  enc_mfma_kernel<<<genc, 256, 0, stream>>>(des, tweet, sw_des, sw_tw, b_des, b_tw, bufA, N);
  enc_small_kernel<<<((size_t)N * 64 + 255) / 256, 256, 0, stream>>>(
      num_prop, cat_prop, w_np, w_cp, b_np, b_cp, bufA, N);

  int gd = (N + 63) / 64;
  int gw = ((size_t)N * 64 + 255) / 256;   // one wave per node

  // ---- x = leaky(x0 @ w_in + b_in) -> bufB ----
  dense_mfma_kernel<true, true><<<gd, 256, 0, stream>>>(bufA, sw_in, b_in, bufB, N);

  // ---- GAT1 ----
  dense_mfma_kernel<false, false><<<gd, 256, 0, stream>>>(bufB, sw_g1, nullptr, bufA, N); // h1
  att_dots_kernel<4><<<gw, 256, 0, stream>>>((const ushort2*)bufA, g1_as, g1_ad, as1, ad1, N);
  agg_kernel<4><<<gw, 256, 0, stream>>>((const ushort2*)bufA, as1, ad1, offs, csr, g1_b, bufB, N); // x1

  // ---- GAT2 ----
  dense_mfma_kernel<false, false><<<gd, 256, 0, stream>>>(bufB, sw_g2, nullptr, bufA, N); // h2
  att_dots_kernel<1><<<gw, 256, 0, stream>>>((const ushort2*)bufA, g2_as, g2_ad, as2, ad2, N);
  agg_kernel<1><<<gw, 256, 0, stream>>>((const ushort2*)bufA, as2, ad2, offs, csr, g2_b, bufB, N); // x2

  // ---- output MLP ----
  dense_mfma_kernel<true, true><<<gd, 256, 0, stream>>>(bufB, sw_o1, b_o1, bufA, N); // t
  final2_kernel<<<(N + 255) / 256, 256, 0, stream>>>(bufA, w_o2, b_o2, (float*)d_out, N);
}